// Round 8
// baseline (1480.701 us; speedup 1.0000x reference)
//
#include <hip/hip_runtime.h>
#include <cmath>

#define VOCABN 32000
#define EE 128
#define HH 256
#define H3 768
#define HOPSN 3
#define HEADSN 4
#define NB 32
#define TMN 50
#define WLENN 20
#define TQN 20
#define NPOS (NB*TMN*WLENN)     // 32000 story positions
#define NQPOS (NB*TQN)          // 640 question positions

// workspace offsets (floats)
#define OFF_MEM    0
#define OFF_Q      (OFF_MEM + NB*TMN*HH)
#define OFF_OK     (OFF_Q + NB*HH)
#define OFF_WB     (OFF_OK + NB*HH)
#define OFF_REP    (OFF_WB + NB*HOPSN*HH)
#define OFF_REAS   (OFF_REP + NB*HEADSN*HH)
#define OFF_Y1     (OFF_REAS + NB*H3)                 // [32][9][768]
#define OFF_PROJ   (OFF_Y1 + NB*9*H3)                 // [32][12][50][256] f32 ; ALSO packed-emb scratch
#define OFF_EMBP   OFF_PROJ                           // uint[VOCAB*64] (8.2MB) — dead before k_proj runs
#define OFF_GI     (OFF_PROJ + NB*12*TMN*HH)          // __fp16[(NPOS+NQPOS)*H3]

typedef __fp16 h2 __attribute__((ext_vector_type(2)));

__device__ __forceinline__ float sigm(float x) { return 1.f / (1.f + expf(-x)); }

__device__ __forceinline__ unsigned packh2(float x, float y) {
    h2 h = __builtin_amdgcn_cvt_pkrtz(x, y);
    return __builtin_bit_cast(unsigned, h);
}

__device__ __forceinline__ float fdot2u(unsigned a, unsigned b, float c) {
    return __builtin_amdgcn_fdot2(__builtin_bit_cast(h2, a),
                                  __builtin_bit_cast(h2, b), c, false);
}

// pack 8 consecutive f32 (2 float4) into one uint4 of f16-pairs
#define LW(v, base, i8) { const float4 A_ = reinterpret_cast<const float4*>(base)[2*(i8)];     \
                          const float4 B_ = reinterpret_cast<const float4*>(base)[2*(i8)+1];   \
                          v.x = packh2(A_.x, A_.y); v.y = packh2(A_.z, A_.w);                  \
                          v.z = packh2(B_.x, B_.y); v.w = packh2(B_.z, B_.w); }

// ---------------- K0: pack embedding table to f16-pairs (into PROJ scratch region) -------------
__global__ __launch_bounds__(256) void k_pack(const float* __restrict__ emb, float* __restrict__ ws)
{
    unsigned* __restrict__ embp = (unsigned*)(ws + OFF_EMBP);
    const int idx = blockIdx.x * 256 + threadIdx.x;
    if (idx < VOCABN * (EE / 2)) {
        const float2 e2 = reinterpret_cast<const float2*>(emb)[idx];
        embp[idx] = packh2(e2.x, e2.y);
    }
}

// ---------------- K1: gi = x @ Wih.T (+folded biases); x via wave-uniform scalar loads ---------
#define GIB 64
__global__ __launch_bounds__(768) void k_gi2(const int* __restrict__ stories,
                                             const int* __restrict__ questions,
                                             const float* __restrict__ iWih,
                                             const float* __restrict__ qWih,
                                             const float* __restrict__ ibih, const float* __restrict__ ibhh,
                                             const float* __restrict__ qbih, const float* __restrict__ qbhh,
                                             float* __restrict__ ws)
{
    __fp16* __restrict__ gi = (__fp16*)(ws + OFF_GI);
    const unsigned* __restrict__ embp = (const unsigned*)(ws + OFF_EMBP);
    const int j = threadIdx.x;             // gate row 0..767
    const bool isq = blockIdx.x >= (NPOS / GIB);
    const int pblk = isq ? (blockIdx.x - NPOS / GIB) : blockIdx.x;
    const int p0 = pblk * GIB;
    const size_t g0 = (isq ? (size_t)NPOS : 0) + (size_t)p0;
    const int* __restrict__ toks = isq ? (questions + p0) : (stories + p0);
    const float* __restrict__ Wih = isq ? qWih : iWih;
    const float* __restrict__ bih = isq ? qbih : ibih;
    const float* __restrict__ bhh = isq ? qbhh : ibhh;
    const float bias = (j < 2 * HH) ? (bih[j] + bhh[j]) : bih[j];
    const float* wrowp = Wih + (size_t)j * EE;
    uint4 v_0, v_1, v_2, v_3, v_4, v_5, v_6, v_7, v_8, v_9, v_10, v_11, v_12, v_13, v_14, v_15;
    LW(v_0, wrowp, 0)  LW(v_1, wrowp, 1)  LW(v_2, wrowp, 2)  LW(v_3, wrowp, 3)
    LW(v_4, wrowp, 4)  LW(v_5, wrowp, 5)  LW(v_6, wrowp, 6)  LW(v_7, wrowp, 7)
    LW(v_8, wrowp, 8)  LW(v_9, wrowp, 9)  LW(v_10, wrowp, 10) LW(v_11, wrowp, 11)
    LW(v_12, wrowp, 12) LW(v_13, wrowp, 13) LW(v_14, wrowp, 14) LW(v_15, wrowp, 15)

#define DOTG(i) { const uint4 xv = xg[i];                                     \
    acc = fdot2u(xv.x, v_##i.x, acc); acc = fdot2u(xv.y, v_##i.y, acc);       \
    acc = fdot2u(xv.z, v_##i.z, acc); acc = fdot2u(xv.w, v_##i.w, acc); }

    for (int p = 0; p < GIB; ++p) {
        const int tok = toks[p];                                 // wave-uniform -> s_load
        const uint4* __restrict__ xg =
            reinterpret_cast<const uint4*>(embp + (size_t)tok * (EE / 2));
        float acc = bias;
        DOTG(0)  DOTG(1)  DOTG(2)  DOTG(3)  DOTG(4)  DOTG(5)  DOTG(6)  DOTG(7)
        DOTG(8)  DOTG(9)  DOTG(10) DOTG(11) DOTG(12) DOTG(13) DOTG(14) DOTG(15)
        gi[(g0 + p) * H3 + j] = (__fp16)acc;
    }
#undef DOTG
}

// ---------------- K2: recurrent GRUs; weights in 48 NAMED uint4 (no alloca -> no scratch) ------
// blocks 0..49: slot chains (640 steps); blocks 50..81: question chains (20 steps)
__global__ __attribute__((amdgpu_flat_work_group_size(512, 512), amdgpu_waves_per_eu(2, 2)))
void k_gru7(
    const float* __restrict__ iWhh, const float* __restrict__ qWhh,
    const float* __restrict__ ibhh, const float* __restrict__ qbhh,
    float* __restrict__ ws)
{
    __shared__ unsigned hp32[HH / 2];      // h as 128 packed f16 pairs
    __shared__ float red[HH * 5];          // stride-5 partial exchange
    const int tid = threadIdx.x;
    const int j = tid & 255, kh = tid >> 8;      // output index, k-half (0/1)
    const int blk = blockIdx.x;
    const bool isq = blk >= TMN;
    const float* __restrict__ Whh = isq ? qWhh : iWhh;
    const float* row0 = Whh + (size_t)j * HH + kh * 128;
    const float* row1 = Whh + (size_t)(HH + j) * HH + kh * 128;
    const float* row2 = Whh + (size_t)(2 * HH + j) * HH + kh * 128;
    uint4 w0_0, w0_1, w0_2, w0_3, w0_4, w0_5, w0_6, w0_7,
          w0_8, w0_9, w0_10, w0_11, w0_12, w0_13, w0_14, w0_15;
    uint4 w1_0, w1_1, w1_2, w1_3, w1_4, w1_5, w1_6, w1_7,
          w1_8, w1_9, w1_10, w1_11, w1_12, w1_13, w1_14, w1_15;
    uint4 w2_0, w2_1, w2_2, w2_3, w2_4, w2_5, w2_6, w2_7,
          w2_8, w2_9, w2_10, w2_11, w2_12, w2_13, w2_14, w2_15;
    LW(w0_0, row0, 0)  LW(w0_1, row0, 1)  LW(w0_2, row0, 2)  LW(w0_3, row0, 3)
    LW(w0_4, row0, 4)  LW(w0_5, row0, 5)  LW(w0_6, row0, 6)  LW(w0_7, row0, 7)
    LW(w0_8, row0, 8)  LW(w0_9, row0, 9)  LW(w0_10, row0, 10) LW(w0_11, row0, 11)
    LW(w0_12, row0, 12) LW(w0_13, row0, 13) LW(w0_14, row0, 14) LW(w0_15, row0, 15)
    LW(w1_0, row1, 0)  LW(w1_1, row1, 1)  LW(w1_2, row1, 2)  LW(w1_3, row1, 3)
    LW(w1_4, row1, 4)  LW(w1_5, row1, 5)  LW(w1_6, row1, 6)  LW(w1_7, row1, 7)
    LW(w1_8, row1, 8)  LW(w1_9, row1, 9)  LW(w1_10, row1, 10) LW(w1_11, row1, 11)
    LW(w1_12, row1, 12) LW(w1_13, row1, 13) LW(w1_14, row1, 14) LW(w1_15, row1, 15)
    LW(w2_0, row2, 0)  LW(w2_1, row2, 1)  LW(w2_2, row2, 2)  LW(w2_3, row2, 3)
    LW(w2_4, row2, 4)  LW(w2_5, row2, 5)  LW(w2_6, row2, 6)  LW(w2_7, row2, 7)
    LW(w2_8, row2, 8)  LW(w2_9, row2, 9)  LW(w2_10, row2, 10) LW(w2_11, row2, 11)
    LW(w2_12, row2, 12) LW(w2_13, row2, 13) LW(w2_14, row2, 14) LW(w2_15, row2, 15)

    float bnH = 0.f, hstate = 0.f;
    if (kh == 0) bnH = (isq ? qbhh : ibhh)[2 * HH + j];
    if (tid < HH / 2) hp32[tid] = 0u;
    const __fp16* __restrict__ gib = (const __fp16*)(ws + OFF_GI)
                                     + (isq ? (size_t)NPOS * H3 : 0);
    float* __restrict__ memv = ws + OFF_MEM;
    float* __restrict__ qv   = ws + OFF_Q;
    __syncthreads();

#define DOT(i) { const uint4 hv = hp4[kh * 16 + (i)];                        \
    a0 = fdot2u(hv.x, w0_##i.x, a0); a0 = fdot2u(hv.y, w0_##i.y, a0);        \
    a0 = fdot2u(hv.z, w0_##i.z, a0); a0 = fdot2u(hv.w, w0_##i.w, a0);        \
    a1 = fdot2u(hv.x, w1_##i.x, a1); a1 = fdot2u(hv.y, w1_##i.y, a1);        \
    a1 = fdot2u(hv.z, w1_##i.z, a1); a1 = fdot2u(hv.w, w1_##i.w, a1);        \
    a2 = fdot2u(hv.x, w2_##i.x, a2); a2 = fdot2u(hv.y, w2_##i.y, a2);        \
    a2 = fdot2u(hv.z, w2_##i.z, a2); a2 = fdot2u(hv.w, w2_##i.w, a2); }

    const int nOuter = isq ? 1 : NB;
    const int c = isq ? (blk - TMN) : blk;
    for (int n = 0; n < nOuter; ++n) {
        for (int t = 0; t < WLENN; ++t) {
            const int pos = isq ? (c * TQN + t) : ((n * TMN + c) * WLENN + t);
            float gir = 0.f, giz = 0.f, gin = 0.f;
            if (kh == 0) {     // issue early, consumed after the FMA chain
                const size_t gb = (size_t)pos * H3;
                gir = (float)gib[gb + j];
                giz = (float)gib[gb + HH + j];
                gin = (float)gib[gb + 2 * HH + j];
            }
            float a0 = 0.f, a1 = 0.f, a2 = 0.f;
            const uint4* hp4 = reinterpret_cast<const uint4*>(hp32);
            DOT(0)  DOT(1)  DOT(2)  DOT(3)  DOT(4)  DOT(5)  DOT(6)  DOT(7)
            DOT(8)  DOT(9)  DOT(10) DOT(11) DOT(12) DOT(13) DOT(14) DOT(15)
            if (kh == 1) { red[j * 5 + 0] = a0; red[j * 5 + 1] = a1; red[j * 5 + 2] = a2; }
            __syncthreads();
            if (kh == 0) {
                const float* rr = red + j * 5;
                const float r  = sigm(a0 + rr[0] + gir);
                const float z  = sigm(a1 + rr[1] + giz);
                const float nn = tanhf(gin + r * (a2 + rr[2] + bnH));
                hstate = (1.f - z) * nn + z * hstate;
                reinterpret_cast<__fp16*>(hp32)[j] = (__fp16)hstate;
                if (t == WLENN - 1) {
                    if (isq) qv[c * HH + j] = hstate;
                    else     memv[(size_t)(n * TMN + c) * HH + j] = hstate;
                }
            }
            __syncthreads();
        }
    }
#undef DOT
}

// ---------------- K3: ft(x), one block per row ----------------
__global__ __launch_bounds__(256) void k_ft(const float* __restrict__ src, float* __restrict__ dst,
                                            const float* __restrict__ W1, const float* __restrict__ b1,
                                            const float* __restrict__ W2, const float* __restrict__ b2)
{
    __shared__ float xr[HH];
    __shared__ float y1[HH];
    const int n = blockIdx.x, j = threadIdx.x;
    xr[j] = src[n * HH + j];
    __syncthreads();
    float acc = b1[j];
    const float4* w1 = reinterpret_cast<const float4*>(W1 + j * HH);
    #pragma unroll 4
    for (int k4 = 0; k4 < HH / 4; ++k4) {
        const float4 w = w1[k4];
        const float4 x = *reinterpret_cast<const float4*>(&xr[k4 * 4]);
        acc = fmaf(x.x, w.x, fmaf(x.y, w.y, fmaf(x.z, w.z, fmaf(x.w, w.w, acc))));
    }
    y1[j] = fmaxf(acc, 0.f);
    __syncthreads();
    acc = b2[j];
    const float4* w2 = reinterpret_cast<const float4*>(W2 + j * HH);
    #pragma unroll 4
    for (int k4 = 0; k4 < HH / 4; ++k4) {
        const float4 w = w2[k4];
        const float4 x = *reinterpret_cast<const float4*>(&y1[k4 * 4]);
        acc = fmaf(x.x, w.x, fmaf(x.y, w.y, fmaf(x.z, w.z, fmaf(x.w, w.w, acc))));
    }
    dst[n * HH + j] = fmaxf(acc, 0.f);
}

// ---------------- K4: proj[n][he][t][e] = tanh(mem[n] @ Wm[he].T)  — hop-independent hoist ------
__global__ __launch_bounds__(256) void k_proj(const float* __restrict__ Wm, float* __restrict__ ws)
{
    __shared__ float mem_s[TMN][HH];   // 51.2 KB
    const int n = blockIdx.x / 12, he = blockIdx.x % 12;
    const int e = threadIdx.x;
    const float* __restrict__ memory = ws + OFF_MEM + n * TMN * HH;
    for (int idx = e; idx < TMN * HH; idx += HH)
        (&mem_s[0][0])[idx] = memory[idx];
    __syncthreads();
    float p[TMN];
    #pragma unroll
    for (int t = 0; t < TMN; ++t) p[t] = 0.f;
    const float4* wrow = reinterpret_cast<const float4*>(Wm + ((size_t)he * HH + e) * HH);
    for (int d4 = 0; d4 < HH / 4; ++d4) {
        const float4 w = wrow[d4];
        #pragma unroll
        for (int t = 0; t < TMN; ++t) {
            const float4 m = *reinterpret_cast<const float4*>(&mem_s[t][d4 * 4]);
            p[t] = fmaf(m.x, w.x, fmaf(m.y, w.y, fmaf(m.z, w.z, fmaf(m.w, w.w, p[t]))));
        }
    }
    float* __restrict__ proj = ws + OFF_PROJ + ((size_t)(n * 12 + he) * TMN) * HH;
    #pragma unroll
    for (int t = 0; t < TMN; ++t) proj[t * HH + e] = tanhf(p[t]);
}

// ---------------- K5: scores+softmax+rep for one hop; block = (n, head) ----------------
__global__ __launch_bounds__(256) void k_attn2(float* __restrict__ ws, int hp)
{
    __shared__ float wred[4][TMN];
    __shared__ float sc[TMN];
    const int n = blockIdx.x / HEADSN, hh = blockIdx.x % HEADSN;
    const int e = threadIdx.x;
    const float* __restrict__ proj = ws + OFF_PROJ + ((size_t)(n * 12 + hp * HEADSN + hh) * TMN) * HH;
    const float* __restrict__ memory = ws + OFF_MEM + n * TMN * HH;
    const float okv = (ws + OFF_OK)[n * HH + e];
    const int lane = e & 63, wv = e >> 6;
    #pragma unroll 10
    for (int t = 0; t < TMN; ++t) {
        float v = proj[t * HH + e] * okv;
        #pragma unroll
        for (int off = 32; off > 0; off >>= 1) v += __shfl_xor(v, off);
        if (lane == 0) wred[wv][t] = v;
    }
    __syncthreads();
    if (e < TMN) sc[e] = wred[0][e] + wred[1][e] + wred[2][e] + wred[3][e];
    __syncthreads();
    if (e == 0) {
        float mx = sc[0];
        for (int t = 1; t < TMN; ++t) mx = fmaxf(mx, sc[t]);
        float sum = 0.f;
        for (int t = 0; t < TMN; ++t) { const float ex = expf(sc[t] - mx); sc[t] = ex; sum += ex; }
        const float inv = 1.f / sum;
        for (int t = 0; t < TMN; ++t) sc[t] *= inv;
    }
    __syncthreads();
    float r = 0.f;
    #pragma unroll 10
    for (int t = 0; t < TMN; ++t) r = fmaf(sc[t], memory[t * HH + e], r);
    (ws + OFF_REP)[(n * HEADSN + hh) * HH + e] = r;
}

// ---------------- K6: buf = rep @ Wo_w.T + Wo_b; o_k = ft(buf) ----------------
__global__ __launch_bounds__(256) void k_buf(const float* __restrict__ Wo_w, const float* __restrict__ Wo_b,
                                             const float* __restrict__ W1, const float* __restrict__ b1,
                                             const float* __restrict__ W2, const float* __restrict__ b2,
                                             float* __restrict__ ws, int hp)
{
    __shared__ float repf[HEADSN * HH];
    __shared__ float bufs[HH];
    __shared__ float y1[HH];
    const int n = blockIdx.x, j = threadIdx.x;
    const float* __restrict__ rep = ws + OFF_REP + n * HEADSN * HH;
    for (int idx = j; idx < HEADSN * HH; idx += HH) repf[idx] = rep[idx];
    __syncthreads();
    float acc = Wo_b[hp * HH + j];
    const float4* wrow = reinterpret_cast<const float4*>(Wo_w + ((size_t)hp * HH + j) * (HEADSN * HH));
    #pragma unroll 4
    for (int c4 = 0; c4 < HEADSN * HH / 4; ++c4) {
        const float4 w = wrow[c4];
        const float4 x = *reinterpret_cast<const float4*>(&repf[c4 * 4]);
        acc = fmaf(x.x, w.x, fmaf(x.y, w.y, fmaf(x.z, w.z, fmaf(x.w, w.w, acc))));
    }
    (ws + OFF_WB)[(n * HOPSN + hp) * HH + j] = acc;
    bufs[j] = acc;
    __syncthreads();
    float a1 = b1[j];
    const float4* w1 = reinterpret_cast<const float4*>(W1 + j * HH);
    #pragma unroll 4
    for (int k4 = 0; k4 < HH / 4; ++k4) {
        const float4 w = w1[k4];
        const float4 x = *reinterpret_cast<const float4*>(&bufs[k4 * 4]);
        a1 = fmaf(x.x, w.x, fmaf(x.y, w.y, fmaf(x.z, w.z, fmaf(x.w, w.w, a1))));
    }
    y1[j] = fmaxf(a1, 0.f);
    __syncthreads();
    float a2 = b2[j];
    const float4* w2 = reinterpret_cast<const float4*>(W2 + j * HH);
    #pragma unroll 4
    for (int k4 = 0; k4 < HH / 4; ++k4) {
        const float4 w = w2[k4];
        const float4 x = *reinterpret_cast<const float4*>(&y1[k4 * 4]);
        a2 = fmaf(x.x, w.x, fmaf(x.y, w.y, fmaf(x.z, w.z, fmaf(x.w, w.w, a2))));
    }
    (ws + OFF_OK)[n * HH + j] = fmaxf(a2, 0.f);
}

// ---------------- K7a: RM layer 1 — y1[n][9][o] ; grid = 32n x 3 o-tiles ----------------
__global__ __launch_bounds__(256) void k_rm1(const float* __restrict__ gW1, const float* __restrict__ gb1,
                                             float* __restrict__ ws)
{
    __shared__ float comb[9 * H3];   // 27.6 KB
    const int n = blockIdx.x / 3, ot = blockIdx.x % 3;
    const int o = ot * 256 + threadIdx.x;
    const float* __restrict__ wb = ws + OFF_WB + n * HOPSN * HH;
    const float* __restrict__ qv = ws + OFF_Q + n * HH;
    for (int idx = threadIdx.x; idx < 9 * H3; idx += 256) {
        const int p = idx / H3, cc = idx - p * H3;
        const int ii = p / 3, jj = p % 3;
        float v;
        if (cc < HH)           v = wb[jj * HH + cc];
        else if (cc < 2 * HH)  v = wb[ii * HH + (cc - HH)];
        else                   v = qv[cc - 2 * HH];
        comb[idx] = v;
    }
    __syncthreads();
    float acc[9];
    const float b = gb1[o];
    #pragma unroll
    for (int p = 0; p < 9; ++p) acc[p] = b;
    const float4* w1 = reinterpret_cast<const float4*>(gW1 + (size_t)o * H3);
    for (int c4 = 0; c4 < H3 / 4; ++c4) {
        const float4 w = w1[c4];
        #pragma unroll
        for (int p = 0; p < 9; ++p) {
            const float4 x = *reinterpret_cast<const float4*>(&comb[p * H3 + c4 * 4]);
            acc[p] = fmaf(x.x, w.x, fmaf(x.y, w.y, fmaf(x.z, w.z, fmaf(x.w, w.w, acc[p]))));
        }
    }
    float* __restrict__ y1 = ws + OFF_Y1 + (size_t)n * 9 * H3;
    #pragma unroll
    for (int p = 0; p < 9; ++p) y1[p * H3 + o] = fmaxf(acc[p], 0.f);
}

// ---------------- K7b: RM layer 2 + pair-sum -> REAS ----------------
__global__ __launch_bounds__(256) void k_rm2(const float* __restrict__ gW2, const float* __restrict__ gb2,
                                             float* __restrict__ ws)
{
    __shared__ float y1s[9 * H3];
    const int n = blockIdx.x / 3, ot = blockIdx.x % 3;
    const int o = ot * 256 + threadIdx.x;
    const float* __restrict__ y1 = ws + OFF_Y1 + (size_t)n * 9 * H3;
    for (int idx = threadIdx.x; idx < 9 * H3; idx += 256) y1s[idx] = y1[idx];
    __syncthreads();
    float acc[9];
    const float b = gb2[o];
    #pragma unroll
    for (int p = 0; p < 9; ++p) acc[p] = b;
    const float4* w2 = reinterpret_cast<const float4*>(gW2 + (size_t)o * H3);
    for (int c4 = 0; c4 < H3 / 4; ++c4) {
        const float4 w = w2[c4];
        #pragma unroll
        for (int p = 0; p < 9; ++p) {
            const float4 x = *reinterpret_cast<const float4*>(&y1s[p * H3 + c4 * 4]);
            acc[p] = fmaf(x.x, w.x, fmaf(x.y, w.y, fmaf(x.z, w.z, fmaf(x.w, w.w, acc[p]))));
        }
    }
    float s = 0.f;
    #pragma unroll
    for (int p = 0; p < 9; ++p) s += fmaxf(acc[p], 0.f);
    (ws + OFF_REAS)[n * H3 + o] = s;
}

// ---------------- K8: out = reasoning @ V_w.T ; 250 blocks x 128 vocab, n split 2-way ----------
#define RST 36   // padded row stride
__global__ __launch_bounds__(256) void k_out(const float* __restrict__ V_w, const float* __restrict__ ws,
                                             float* __restrict__ out)
{
    __shared__ float rsT[H3 * RST];   // transposed reasoning [d][n], 110 KB
    const int tid = threadIdx.x;
    const int v = blockIdx.x * 128 + (tid & 127);
    const int nh = tid >> 7;
    for (int idx = tid; idx < NB * H3; idx += 256) {
        const int n = idx / H3, d = idx - n * H3;
        rsT[d * RST + n] = (ws + OFF_REAS)[idx];
    }
    __syncthreads();
    float acc[16];
    #pragma unroll
    for (int i = 0; i < 16; ++i) acc[i] = 0.f;
    const float4* vw = reinterpret_cast<const float4*>(V_w + (size_t)v * H3);
    for (int d4 = 0; d4 < H3 / 4; ++d4) {
        const float4 w = vw[d4];
        #pragma unroll
        for (int dd = 0; dd < 4; ++dd) {
            const float wd = (dd == 0) ? w.x : (dd == 1) ? w.y : (dd == 2) ? w.z : w.w;
            const float* rr = &rsT[(d4 * 4 + dd) * RST + nh * 16];
            #pragma unroll
            for (int q = 0; q < 4; ++q) {
                const float4 r4 = *reinterpret_cast<const float4*>(rr + 4 * q);
                acc[4 * q + 0] = fmaf(wd, r4.x, acc[4 * q + 0]);
                acc[4 * q + 1] = fmaf(wd, r4.y, acc[4 * q + 1]);
                acc[4 * q + 2] = fmaf(wd, r4.z, acc[4 * q + 2]);
                acc[4 * q + 3] = fmaf(wd, r4.w, acc[4 * q + 3]);
            }
        }
    }
    #pragma unroll
    for (int i = 0; i < 16; ++i)
        out[(size_t)(nh * 16 + i) * VOCABN + v] = acc[i];
}

extern "C" void kernel_launch(void* const* d_in, const int* in_sizes, int n_in,
                              void* d_out, int out_size, void* d_ws, size_t ws_size,
                              hipStream_t stream)
{
    const int*   stories   = (const int*)d_in[0];
    const int*   questions = (const int*)d_in[1];
    const float* emb   = (const float*)d_in[2];
    const float* qWih  = (const float*)d_in[3];
    const float* qWhh  = (const float*)d_in[4];
    const float* qbih  = (const float*)d_in[5];
    const float* qbhh  = (const float*)d_in[6];
    const float* iWih  = (const float*)d_in[7];
    const float* iWhh  = (const float*)d_in[8];
    const float* ibih  = (const float*)d_in[9];
    const float* ibhh  = (const float*)d_in[10];
    const float* Wm    = (const float*)d_in[11];
    const float* Wo_w  = (const float*)d_in[12];
    const float* Wo_b  = (const float*)d_in[13];
    const float* ftW1  = (const float*)d_in[14];
    const float* ftb1  = (const float*)d_in[15];
    const float* ftW2  = (const float*)d_in[16];
    const float* ftb2  = (const float*)d_in[17];
    const float* gW1   = (const float*)d_in[18];
    const float* gb1   = (const float*)d_in[19];
    const float* gW2   = (const float*)d_in[20];
    const float* gb2   = (const float*)d_in[21];
    const float* V_w   = (const float*)d_in[22];
    float* ws  = (float*)d_ws;
    float* out = (float*)d_out;

    hipLaunchKernelGGL(k_pack, dim3((VOCABN * (EE / 2) + 255) / 256), dim3(256), 0, stream, emb, ws);
    hipLaunchKernelGGL(k_gi2, dim3((NPOS + NQPOS) / GIB), dim3(H3), 0, stream,
                       stories, questions, iWih, qWih, ibih, ibhh, qbih, qbhh, ws);
    hipLaunchKernelGGL(k_gru7, dim3(TMN + NB), dim3(512), 0, stream,
                       iWhh, qWhh, ibhh, qbhh, ws);
    hipLaunchKernelGGL(k_ft, dim3(NB), dim3(HH), 0, stream, ws + OFF_Q, ws + OFF_OK, ftW1, ftb1, ftW2, ftb2);
    hipLaunchKernelGGL(k_proj, dim3(NB * 12), dim3(256), 0, stream, Wm, ws);
    for (int hp = 0; hp < HOPSN; ++hp) {
        hipLaunchKernelGGL(k_attn2, dim3(NB * HEADSN), dim3(256), 0, stream, ws, hp);
        hipLaunchKernelGGL(k_buf, dim3(NB), dim3(256), 0, stream, Wo_w, Wo_b, ftW1, ftb1, ftW2, ftb2, ws, hp);
    }
    hipLaunchKernelGGL(k_rm1, dim3(NB * 3), dim3(256), 0, stream, gW1, gb1, ws);
    hipLaunchKernelGGL(k_rm2, dim3(NB * 3), dim3(256), 0, stream, gW2, gb2, ws);
    hipLaunchKernelGGL(k_out, dim3(VOCABN / 128), dim3(256), 0, stream, V_w, ws, out);
}

// Round 9
// 1360.767 us; speedup vs baseline: 1.0881x; 1.0881x over previous
//
#include <hip/hip_runtime.h>
#include <cmath>

#define VOCABN 32000
#define EE 128
#define HH 256
#define H3 768
#define HOPSN 3
#define HEADSN 4
#define NB 32
#define TMN 50
#define WLENN 20
#define TQN 20
#define NPOS (NB*TMN*WLENN)     // 32000 story positions
#define NQPOS (NB*TQN)          // 640 question positions

// workspace offsets (floats)
#define OFF_MEM    0
#define OFF_Q      (OFF_MEM + NB*TMN*HH)
#define OFF_OK     (OFF_Q + NB*HH)
#define OFF_WB     (OFF_OK + NB*HH)
#define OFF_REP    (OFF_WB + NB*HOPSN*HH)
#define OFF_REAS   (OFF_REP + NB*HEADSN*HH)
#define OFF_Y1     (OFF_REAS + NB*H3)                 // [32][9][768]
#define OFF_PROJ   (OFF_Y1 + NB*9*H3)                 // [32][12][50][256] f32
#define OFF_GI     (OFF_PROJ + NB*12*TMN*HH)          // __fp16[(NPOS+NQPOS)*H3]

typedef __fp16 h2 __attribute__((ext_vector_type(2)));

__device__ __forceinline__ float sigm(float x) { return 1.f / (1.f + expf(-x)); }

__device__ __forceinline__ unsigned packh2(float x, float y) {
    h2 h = __builtin_amdgcn_cvt_pkrtz(x, y);
    return __builtin_bit_cast(unsigned, h);
}

__device__ __forceinline__ float fdot2u(unsigned a, unsigned b, float c) {
    return __builtin_amdgcn_fdot2(__builtin_bit_cast(h2, a),
                                  __builtin_bit_cast(h2, b), c, false);
}

// pack 8 consecutive f32 (2 float4) into one uint4 of f16-pairs
#define LW(v, base, i8) { const float4 A_ = reinterpret_cast<const float4*>(base)[2*(i8)];     \
                          const float4 B_ = reinterpret_cast<const float4*>(base)[2*(i8)+1];   \
                          v.x = packh2(A_.x, A_.y); v.y = packh2(A_.z, A_.w);                  \
                          v.z = packh2(B_.x, B_.y); v.w = packh2(B_.z, B_.w); }

// ---------------- K1: gi = x @ Wih.T (+folded biases); LDS-staged x, named-reg weights ---------
#define GIB 64
__global__ __launch_bounds__(768) void k_gi(const int* __restrict__ stories,
                                            const int* __restrict__ questions,
                                            const float* __restrict__ emb,
                                            const float* __restrict__ iWih,
                                            const float* __restrict__ qWih,
                                            const float* __restrict__ ibih, const float* __restrict__ ibhh,
                                            const float* __restrict__ qbih, const float* __restrict__ qbhh,
                                            float* __restrict__ ws)
{
    __shared__ unsigned xs[GIB][EE / 2];   // 64 pos x 64 packed-f16 pairs (16 KB)
    __fp16* __restrict__ gi = (__fp16*)(ws + OFF_GI);
    const int j = threadIdx.x;             // gate row 0..767
    const bool isq = blockIdx.x >= (NPOS / GIB);
    const int pblk = isq ? (blockIdx.x - NPOS / GIB) : blockIdx.x;
    const int p0 = pblk * GIB;
    const size_t g0 = (isq ? (size_t)NPOS : 0) + (size_t)p0;
    const int* __restrict__ toks = isq ? (questions + p0) : (stories + p0);
    const float* __restrict__ Wih = isq ? qWih : iWih;
    const float* __restrict__ bih = isq ? qbih : ibih;
    const float* __restrict__ bhh = isq ? qbhh : ibhh;
    const float bias = (j < 2 * HH) ? (bih[j] + bhh[j]) : bih[j];
    const float* wrowp = Wih + (size_t)j * EE;
    uint4 v_0, v_1, v_2, v_3, v_4, v_5, v_6, v_7, v_8, v_9, v_10, v_11, v_12, v_13, v_14, v_15;
    LW(v_0, wrowp, 0)  LW(v_1, wrowp, 1)  LW(v_2, wrowp, 2)  LW(v_3, wrowp, 3)
    LW(v_4, wrowp, 4)  LW(v_5, wrowp, 5)  LW(v_6, wrowp, 6)  LW(v_7, wrowp, 7)
    LW(v_8, wrowp, 8)  LW(v_9, wrowp, 9)  LW(v_10, wrowp, 10) LW(v_11, wrowp, 11)
    LW(v_12, wrowp, 12) LW(v_13, wrowp, 13) LW(v_14, wrowp, 14) LW(v_15, wrowp, 15)

    for (int idx = j; idx < GIB * (EE / 2); idx += H3) {
        const int p = idx >> 6, c = idx & 63;
        const int tok = toks[p];
        const float2 e2 = reinterpret_cast<const float2*>(emb + (size_t)tok * EE)[c];
        xs[p][c] = packh2(e2.x, e2.y);
    }
    __syncthreads();

#define DOTG(i) { const uint4 xv = x4[i];                                     \
    acc = fdot2u(xv.x, v_##i.x, acc); acc = fdot2u(xv.y, v_##i.y, acc);       \
    acc = fdot2u(xv.z, v_##i.z, acc); acc = fdot2u(xv.w, v_##i.w, acc); }

    for (int p = 0; p < GIB; ++p) {
        const uint4* x4 = reinterpret_cast<const uint4*>(&xs[p][0]);
        float acc = bias;
        DOTG(0)  DOTG(1)  DOTG(2)  DOTG(3)  DOTG(4)  DOTG(5)  DOTG(6)  DOTG(7)
        DOTG(8)  DOTG(9)  DOTG(10) DOTG(11) DOTG(12) DOTG(13) DOTG(14) DOTG(15)
        gi[(g0 + p) * H3 + j] = (__fp16)acc;
    }
#undef DOTG
}

// ---------------- K2: recurrent GRUs; 88KB LDS forces 1 WG/CU -> 256-VGPR RA budget ------------
// blocks 0..49: slot chains (640 steps); blocks 50..81: question chains (20 steps)
#define LDSF 22016   // 88,064 B > 80 KB -> exactly 1 workgroup per CU
__global__ __attribute__((amdgpu_flat_work_group_size(512, 512), amdgpu_waves_per_eu(2, 2)))
void k_gru8(
    const float* __restrict__ iWhh, const float* __restrict__ qWhh,
    const float* __restrict__ ibhh, const float* __restrict__ qbhh,
    float* __restrict__ ws)
{
    __shared__ float ldsb[LDSF];           // front: hp32 (128 u32) | red (1280 f32)
    unsigned* hp32 = (unsigned*)ldsb;      // h as 128 packed f16 pairs
    float* red = ldsb + 128;               // stride-5 partial exchange
    const int tid = threadIdx.x;
    const int j = tid & 255, kh = tid >> 8;      // output index, k-half (0/1)
    const int blk = blockIdx.x;
    const bool isq = blk >= TMN;
    const float* __restrict__ Whh = isq ? qWhh : iWhh;
    const float* row0 = Whh + (size_t)j * HH + kh * 128;
    const float* row1 = Whh + (size_t)(HH + j) * HH + kh * 128;
    const float* row2 = Whh + (size_t)(2 * HH + j) * HH + kh * 128;
    uint4 w0_0, w0_1, w0_2, w0_3, w0_4, w0_5, w0_6, w0_7,
          w0_8, w0_9, w0_10, w0_11, w0_12, w0_13, w0_14, w0_15;
    uint4 w1_0, w1_1, w1_2, w1_3, w1_4, w1_5, w1_6, w1_7,
          w1_8, w1_9, w1_10, w1_11, w1_12, w1_13, w1_14, w1_15;
    uint4 w2_0, w2_1, w2_2, w2_3, w2_4, w2_5, w2_6, w2_7,
          w2_8, w2_9, w2_10, w2_11, w2_12, w2_13, w2_14, w2_15;
    LW(w0_0, row0, 0)  LW(w0_1, row0, 1)  LW(w0_2, row0, 2)  LW(w0_3, row0, 3)
    LW(w0_4, row0, 4)  LW(w0_5, row0, 5)  LW(w0_6, row0, 6)  LW(w0_7, row0, 7)
    LW(w0_8, row0, 8)  LW(w0_9, row0, 9)  LW(w0_10, row0, 10) LW(w0_11, row0, 11)
    LW(w0_12, row0, 12) LW(w0_13, row0, 13) LW(w0_14, row0, 14) LW(w0_15, row0, 15)
    LW(w1_0, row1, 0)  LW(w1_1, row1, 1)  LW(w1_2, row1, 2)  LW(w1_3, row1, 3)
    LW(w1_4, row1, 4)  LW(w1_5, row1, 5)  LW(w1_6, row1, 6)  LW(w1_7, row1, 7)
    LW(w1_8, row1, 8)  LW(w1_9, row1, 9)  LW(w1_10, row1, 10) LW(w1_11, row1, 11)
    LW(w1_12, row1, 12) LW(w1_13, row1, 13) LW(w1_14, row1, 14) LW(w1_15, row1, 15)
    LW(w2_0, row2, 0)  LW(w2_1, row2, 1)  LW(w2_2, row2, 2)  LW(w2_3, row2, 3)
    LW(w2_4, row2, 4)  LW(w2_5, row2, 5)  LW(w2_6, row2, 6)  LW(w2_7, row2, 7)
    LW(w2_8, row2, 8)  LW(w2_9, row2, 9)  LW(w2_10, row2, 10) LW(w2_11, row2, 11)
    LW(w2_12, row2, 12) LW(w2_13, row2, 13) LW(w2_14, row2, 14) LW(w2_15, row2, 15)

    float bnH = 0.f, hstate = 0.f;
    if (kh == 0) bnH = (isq ? qbhh : ibhh)[2 * HH + j];
    if (tid < HH / 2) hp32[tid] = 0u;
    const __fp16* __restrict__ gib = (const __fp16*)(ws + OFF_GI)
                                     + (isq ? (size_t)NPOS * H3 : 0);
    float* __restrict__ memv = ws + OFF_MEM;
    float* __restrict__ qv   = ws + OFF_Q;
    __syncthreads();

#define DOT(i) { const uint4 hv = hp4[kh * 16 + (i)];                        \
    a0 = fdot2u(hv.x, w0_##i.x, a0); a0 = fdot2u(hv.y, w0_##i.y, a0);        \
    a0 = fdot2u(hv.z, w0_##i.z, a0); a0 = fdot2u(hv.w, w0_##i.w, a0);        \
    a1 = fdot2u(hv.x, w1_##i.x, a1); a1 = fdot2u(hv.y, w1_##i.y, a1);        \
    a1 = fdot2u(hv.z, w1_##i.z, a1); a1 = fdot2u(hv.w, w1_##i.w, a1);        \
    a2 = fdot2u(hv.x, w2_##i.x, a2); a2 = fdot2u(hv.y, w2_##i.y, a2);        \
    a2 = fdot2u(hv.z, w2_##i.z, a2); a2 = fdot2u(hv.w, w2_##i.w, a2); }

    const int nOuter = isq ? 1 : NB;
    const int c = isq ? (blk - TMN) : blk;
    for (int n = 0; n < nOuter; ++n) {
        for (int t = 0; t < WLENN; ++t) {
            const int pos = isq ? (c * TQN + t) : ((n * TMN + c) * WLENN + t);
            float gir = 0.f, giz = 0.f, gin = 0.f;
            if (kh == 0) {     // issue early, consumed after the FMA chain
                const size_t gb = (size_t)pos * H3;
                gir = (float)gib[gb + j];
                giz = (float)gib[gb + HH + j];
                gin = (float)gib[gb + 2 * HH + j];
            }
            float a0 = 0.f, a1 = 0.f, a2 = 0.f;
            const uint4* hp4 = reinterpret_cast<const uint4*>(hp32);
            DOT(0)  DOT(1)  DOT(2)  DOT(3)  DOT(4)  DOT(5)  DOT(6)  DOT(7)
            DOT(8)  DOT(9)  DOT(10) DOT(11) DOT(12) DOT(13) DOT(14) DOT(15)
            if (kh == 1) { red[j * 5 + 0] = a0; red[j * 5 + 1] = a1; red[j * 5 + 2] = a2; }
            __syncthreads();
            if (kh == 0) {
                const float* rr = red + j * 5;
                const float r  = sigm(a0 + rr[0] + gir);
                const float z  = sigm(a1 + rr[1] + giz);
                const float nn = tanhf(gin + r * (a2 + rr[2] + bnH));
                hstate = (1.f - z) * nn + z * hstate;
                reinterpret_cast<__fp16*>(hp32)[j] = (__fp16)hstate;
                if (t == WLENN - 1) {
                    if (isq) qv[c * HH + j] = hstate;
                    else     memv[(size_t)(n * TMN + c) * HH + j] = hstate;
                }
            }
            __syncthreads();
        }
    }
#undef DOT
}

// ---------------- K3: ft(x), one block per row ----------------
__global__ __launch_bounds__(256) void k_ft(const float* __restrict__ src, float* __restrict__ dst,
                                            const float* __restrict__ W1, const float* __restrict__ b1,
                                            const float* __restrict__ W2, const float* __restrict__ b2)
{
    __shared__ float xr[HH];
    __shared__ float y1[HH];
    const int n = blockIdx.x, j = threadIdx.x;
    xr[j] = src[n * HH + j];
    __syncthreads();
    float acc = b1[j];
    const float4* w1 = reinterpret_cast<const float4*>(W1 + j * HH);
    #pragma unroll 4
    for (int k4 = 0; k4 < HH / 4; ++k4) {
        const float4 w = w1[k4];
        const float4 x = *reinterpret_cast<const float4*>(&xr[k4 * 4]);
        acc = fmaf(x.x, w.x, fmaf(x.y, w.y, fmaf(x.z, w.z, fmaf(x.w, w.w, acc))));
    }
    y1[j] = fmaxf(acc, 0.f);
    __syncthreads();
    acc = b2[j];
    const float4* w2 = reinterpret_cast<const float4*>(W2 + j * HH);
    #pragma unroll 4
    for (int k4 = 0; k4 < HH / 4; ++k4) {
        const float4 w = w2[k4];
        const float4 x = *reinterpret_cast<const float4*>(&y1[k4 * 4]);
        acc = fmaf(x.x, w.x, fmaf(x.y, w.y, fmaf(x.z, w.z, fmaf(x.w, w.w, acc))));
    }
    dst[n * HH + j] = fmaxf(acc, 0.f);
}

// ---------------- K4: proj[n][he][t][e] = tanh(mem[n] @ Wm[he].T)  — hop-independent hoist ------
__global__ __launch_bounds__(256) void k_proj(const float* __restrict__ Wm, float* __restrict__ ws)
{
    __shared__ float mem_s[TMN][HH];   // 51.2 KB
    const int n = blockIdx.x / 12, he = blockIdx.x % 12;
    const int e = threadIdx.x;
    const float* __restrict__ memory = ws + OFF_MEM + n * TMN * HH;
    for (int idx = e; idx < TMN * HH; idx += HH)
        (&mem_s[0][0])[idx] = memory[idx];
    __syncthreads();
    float p[TMN];
    #pragma unroll
    for (int t = 0; t < TMN; ++t) p[t] = 0.f;
    const float4* wrow = reinterpret_cast<const float4*>(Wm + ((size_t)he * HH + e) * HH);
    for (int d4 = 0; d4 < HH / 4; ++d4) {
        const float4 w = wrow[d4];
        #pragma unroll
        for (int t = 0; t < TMN; ++t) {
            const float4 m = *reinterpret_cast<const float4*>(&mem_s[t][d4 * 4]);
            p[t] = fmaf(m.x, w.x, fmaf(m.y, w.y, fmaf(m.z, w.z, fmaf(m.w, w.w, p[t]))));
        }
    }
    float* __restrict__ proj = ws + OFF_PROJ + ((size_t)(n * 12 + he) * TMN) * HH;
    #pragma unroll
    for (int t = 0; t < TMN; ++t) proj[t * HH + e] = tanhf(p[t]);
}

// ---------------- K5: scores+softmax+rep for one hop; block = (n, head) ----------------
__global__ __launch_bounds__(256) void k_attn2(float* __restrict__ ws, int hp)
{
    __shared__ float wred[4][TMN];
    __shared__ float sc[TMN];
    const int n = blockIdx.x / HEADSN, hh = blockIdx.x % HEADSN;
    const int e = threadIdx.x;
    const float* __restrict__ proj = ws + OFF_PROJ + ((size_t)(n * 12 + hp * HEADSN + hh) * TMN) * HH;
    const float* __restrict__ memory = ws + OFF_MEM + n * TMN * HH;
    const float okv = (ws + OFF_OK)[n * HH + e];
    const int lane = e & 63, wv = e >> 6;
    #pragma unroll 10
    for (int t = 0; t < TMN; ++t) {
        float v = proj[t * HH + e] * okv;
        #pragma unroll
        for (int off = 32; off > 0; off >>= 1) v += __shfl_xor(v, off);
        if (lane == 0) wred[wv][t] = v;
    }
    __syncthreads();
    if (e < TMN) sc[e] = wred[0][e] + wred[1][e] + wred[2][e] + wred[3][e];
    __syncthreads();
    if (e == 0) {
        float mx = sc[0];
        for (int t = 1; t < TMN; ++t) mx = fmaxf(mx, sc[t]);
        float sum = 0.f;
        for (int t = 0; t < TMN; ++t) { const float ex = expf(sc[t] - mx); sc[t] = ex; sum += ex; }
        const float inv = 1.f / sum;
        for (int t = 0; t < TMN; ++t) sc[t] *= inv;
    }
    __syncthreads();
    float r = 0.f;
    #pragma unroll 10
    for (int t = 0; t < TMN; ++t) r = fmaf(sc[t], memory[t * HH + e], r);
    (ws + OFF_REP)[(n * HEADSN + hh) * HH + e] = r;
}

// ---------------- K6: buf = rep @ Wo_w.T + Wo_b; o_k = ft(buf) ----------------
__global__ __launch_bounds__(256) void k_buf(const float* __restrict__ Wo_w, const float* __restrict__ Wo_b,
                                             const float* __restrict__ W1, const float* __restrict__ b1,
                                             const float* __restrict__ W2, const float* __restrict__ b2,
                                             float* __restrict__ ws, int hp)
{
    __shared__ float repf[HEADSN * HH];
    __shared__ float bufs[HH];
    __shared__ float y1[HH];
    const int n = blockIdx.x, j = threadIdx.x;
    const float* __restrict__ rep = ws + OFF_REP + n * HEADSN * HH;
    for (int idx = j; idx < HEADSN * HH; idx += HH) repf[idx] = rep[idx];
    __syncthreads();
    float acc = Wo_b[hp * HH + j];
    const float4* wrow = reinterpret_cast<const float4*>(Wo_w + ((size_t)hp * HH + j) * (HEADSN * HH));
    #pragma unroll 4
    for (int c4 = 0; c4 < HEADSN * HH / 4; ++c4) {
        const float4 w = wrow[c4];
        const float4 x = *reinterpret_cast<const float4*>(&repf[c4 * 4]);
        acc = fmaf(x.x, w.x, fmaf(x.y, w.y, fmaf(x.z, w.z, fmaf(x.w, w.w, acc))));
    }
    (ws + OFF_WB)[(n * HOPSN + hp) * HH + j] = acc;
    bufs[j] = acc;
    __syncthreads();
    float a1 = b1[j];
    const float4* w1 = reinterpret_cast<const float4*>(W1 + j * HH);
    #pragma unroll 4
    for (int k4 = 0; k4 < HH / 4; ++k4) {
        const float4 w = w1[k4];
        const float4 x = *reinterpret_cast<const float4*>(&bufs[k4 * 4]);
        a1 = fmaf(x.x, w.x, fmaf(x.y, w.y, fmaf(x.z, w.z, fmaf(x.w, w.w, a1))));
    }
    y1[j] = fmaxf(a1, 0.f);
    __syncthreads();
    float a2 = b2[j];
    const float4* w2 = reinterpret_cast<const float4*>(W2 + j * HH);
    #pragma unroll 4
    for (int k4 = 0; k4 < HH / 4; ++k4) {
        const float4 w = w2[k4];
        const float4 x = *reinterpret_cast<const float4*>(&y1[k4 * 4]);
        a2 = fmaf(x.x, w.x, fmaf(x.y, w.y, fmaf(x.z, w.z, fmaf(x.w, w.w, a2))));
    }
    (ws + OFF_OK)[n * HH + j] = fmaxf(a2, 0.f);
}

// ---------------- K7a: RM layer 1 — y1[n][9][o] ; grid = 32n x 3 o-tiles ----------------
__global__ __launch_bounds__(256) void k_rm1(const float* __restrict__ gW1, const float* __restrict__ gb1,
                                             float* __restrict__ ws)
{
    __shared__ float comb[9 * H3];   // 27.6 KB
    const int n = blockIdx.x / 3, ot = blockIdx.x % 3;
    const int o = ot * 256 + threadIdx.x;
    const float* __restrict__ wb = ws + OFF_WB + n * HOPSN * HH;
    const float* __restrict__ qv = ws + OFF_Q + n * HH;
    for (int idx = threadIdx.x; idx < 9 * H3; idx += 256) {
        const int p = idx / H3, cc = idx - p * H3;
        const int ii = p / 3, jj = p % 3;
        float v;
        if (cc < HH)           v = wb[jj * HH + cc];
        else if (cc < 2 * HH)  v = wb[ii * HH + (cc - HH)];
        else                   v = qv[cc - 2 * HH];
        comb[idx] = v;
    }
    __syncthreads();
    float acc[9];
    const float b = gb1[o];
    #pragma unroll
    for (int p = 0; p < 9; ++p) acc[p] = b;
    const float4* w1 = reinterpret_cast<const float4*>(gW1 + (size_t)o * H3);
    for (int c4 = 0; c4 < H3 / 4; ++c4) {
        const float4 w = w1[c4];
        #pragma unroll
        for (int p = 0; p < 9; ++p) {
            const float4 x = *reinterpret_cast<const float4*>(&comb[p * H3 + c4 * 4]);
            acc[p] = fmaf(x.x, w.x, fmaf(x.y, w.y, fmaf(x.z, w.z, fmaf(x.w, w.w, acc[p]))));
        }
    }
    float* __restrict__ y1 = ws + OFF_Y1 + (size_t)n * 9 * H3;
    #pragma unroll
    for (int p = 0; p < 9; ++p) y1[p * H3 + o] = fmaxf(acc[p], 0.f);
}

// ---------------- K7b: RM layer 2 + pair-sum -> REAS ----------------
__global__ __launch_bounds__(256) void k_rm2(const float* __restrict__ gW2, const float* __restrict__ gb2,
                                             float* __restrict__ ws)
{
    __shared__ float y1s[9 * H3];
    const int n = blockIdx.x / 3, ot = blockIdx.x % 3;
    const int o = ot * 256 + threadIdx.x;
    const float* __restrict__ y1 = ws + OFF_Y1 + (size_t)n * 9 * H3;
    for (int idx = threadIdx.x; idx < 9 * H3; idx += 256) y1s[idx] = y1[idx];
    __syncthreads();
    float acc[9];
    const float b = gb2[o];
    #pragma unroll
    for (int p = 0; p < 9; ++p) acc[p] = b;
    const float4* w2 = reinterpret_cast<const float4*>(gW2 + (size_t)o * H3);
    for (int c4 = 0; c4 < H3 / 4; ++c4) {
        const float4 w = w2[c4];
        #pragma unroll
        for (int p = 0; p < 9; ++p) {
            const float4 x = *reinterpret_cast<const float4*>(&y1s[p * H3 + c4 * 4]);
            acc[p] = fmaf(x.x, w.x, fmaf(x.y, w.y, fmaf(x.z, w.z, fmaf(x.w, w.w, acc[p]))));
        }
    }
    float s = 0.f;
    #pragma unroll
    for (int p = 0; p < 9; ++p) s += fmaxf(acc[p], 0.f);
    (ws + OFF_REAS)[n * H3 + o] = s;
}

// ---------------- K8: out = reasoning @ V_w.T ; 250 blocks x 128 vocab, n split 2-way ----------
#define RST 36   // padded row stride
__global__ __launch_bounds__(256) void k_out(const float* __restrict__ V_w, const float* __restrict__ ws,
                                             float* __restrict__ out)
{
    __shared__ float rsT[H3 * RST];   // transposed reasoning [d][n], 110 KB
    const int tid = threadIdx.x;
    const int v = blockIdx.x * 128 + (tid & 127);
    const int nh = tid >> 7;
    for (int idx = tid; idx < NB * H3; idx += 256) {
        const int n = idx / H3, d = idx - n * H3;
        rsT[d * RST + n] = (ws + OFF_REAS)[idx];
    }
    __syncthreads();
    float acc[16];
    #pragma unroll
    for (int i = 0; i < 16; ++i) acc[i] = 0.f;
    const float4* vw = reinterpret_cast<const float4*>(V_w + (size_t)v * H3);
    for (int d4 = 0; d4 < H3 / 4; ++d4) {
        const float4 w = vw[d4];
        #pragma unroll
        for (int dd = 0; dd < 4; ++dd) {
            const float wd = (dd == 0) ? w.x : (dd == 1) ? w.y : (dd == 2) ? w.z : w.w;
            const float* rr = &rsT[(d4 * 4 + dd) * RST + nh * 16];
            #pragma unroll
            for (int q = 0; q < 4; ++q) {
                const float4 r4 = *reinterpret_cast<const float4*>(rr + 4 * q);
                acc[4 * q + 0] = fmaf(wd, r4.x, acc[4 * q + 0]);
                acc[4 * q + 1] = fmaf(wd, r4.y, acc[4 * q + 1]);
                acc[4 * q + 2] = fmaf(wd, r4.z, acc[4 * q + 2]);
                acc[4 * q + 3] = fmaf(wd, r4.w, acc[4 * q + 3]);
            }
        }
    }
    #pragma unroll
    for (int i = 0; i < 16; ++i)
        out[(size_t)(nh * 16 + i) * VOCABN + v] = acc[i];
}

extern "C" void kernel_launch(void* const* d_in, const int* in_sizes, int n_in,
                              void* d_out, int out_size, void* d_ws, size_t ws_size,
                              hipStream_t stream)
{
    const int*   stories   = (const int*)d_in[0];
    const int*   questions = (const int*)d_in[1];
    const float* emb   = (const float*)d_in[2];
    const float* qWih  = (const float*)d_in[3];
    const float* qWhh  = (const float*)d_in[4];
    const float* qbih  = (const float*)d_in[5];
    const float* qbhh  = (const float*)d_in[6];
    const float* iWih  = (const float*)d_in[7];
    const float* iWhh  = (const float*)d_in[8];
    const float* ibih  = (const float*)d_in[9];
    const float* ibhh  = (const float*)d_in[10];
    const float* Wm    = (const float*)d_in[11];
    const float* Wo_w  = (const float*)d_in[12];
    const float* Wo_b  = (const float*)d_in[13];
    const float* ftW1  = (const float*)d_in[14];
    const float* ftb1  = (const float*)d_in[15];
    const float* ftW2  = (const float*)d_in[16];
    const float* ftb2  = (const float*)d_in[17];
    const float* gW1   = (const float*)d_in[18];
    const float* gb1   = (const float*)d_in[19];
    const float* gW2   = (const float*)d_in[20];
    const float* gb2   = (const float*)d_in[21];
    const float* V_w   = (const float*)d_in[22];
    float* ws  = (float*)d_ws;
    float* out = (float*)d_out;

    hipLaunchKernelGGL(k_gi, dim3((NPOS + NQPOS) / GIB), dim3(H3), 0, stream,
                       stories, questions, emb, iWih, qWih, ibih, ibhh, qbih, qbhh, ws);
    hipLaunchKernelGGL(k_gru8, dim3(TMN + NB), dim3(512), 0, stream,
                       iWhh, qWhh, ibhh, qbhh, ws);
    hipLaunchKernelGGL(k_ft, dim3(NB), dim3(HH), 0, stream, ws + OFF_Q, ws + OFF_OK, ftW1, ftb1, ftW2, ftb2);
    hipLaunchKernelGGL(k_proj, dim3(NB * 12), dim3(256), 0, stream, Wm, ws);
    for (int hp = 0; hp < HOPSN; ++hp) {
        hipLaunchKernelGGL(k_attn2, dim3(NB * HEADSN), dim3(256), 0, stream, ws, hp);
        hipLaunchKernelGGL(k_buf, dim3(NB), dim3(256), 0, stream, Wo_w, Wo_b, ftW1, ftb1, ftW2, ftb2, ws, hp);
    }
    hipLaunchKernelGGL(k_rm1, dim3(NB * 3), dim3(256), 0, stream, gW1, gb1, ws);
    hipLaunchKernelGGL(k_rm2, dim3(NB * 3), dim3(256), 0, stream, gW2, gb2, ws);
    hipLaunchKernelGGL(k_out, dim3(VOCABN / 128), dim3(256), 0, stream, V_w, ws, out);
}